// Round 1
// baseline (1285.920 us; speedup 1.0000x reference)
//
#include <hip/hip_runtime.h>
#include <math.h>

#define DIM 256

// lower_bound over sorted batch array; handles int32 or int64 storage.
__device__ __forceinline__ int lbound(const void* batch, bool is64, int n, int val) {
    int lo = 0, hi = n;
    if (is64) {
        const long long* a = (const long long*)batch;
        long long v = (long long)val;
        while (lo < hi) { int mid = (lo + hi) >> 1; if (a[mid] < v) lo = mid + 1; else hi = mid; }
    } else {
        const int* a = (const int*)batch;
        while (lo < hi) { int mid = (lo + hi) >> 1; if (a[mid] < val) lo = mid + 1; else hi = mid; }
    }
    return lo;
}

__global__ __launch_bounds__(256, 8) void readout_kernel(
    const float* __restrict__ x,
    const void*  __restrict__ batch,
    const float* __restrict__ W,
    const float* __restrict__ b,
    float*       __restrict__ out,
    int n)
{
    const int g    = blockIdx.x;
    const int tid  = threadIdx.x;
    const int w    = tid >> 6;    // wave id 0..3
    const int lane = tid & 63;    // lane id 0..63

    // --- batch dtype sniff (block-uniform): int64 storage => int32 view's
    // last word is the high word of the median element == 0, while the word
    // before it (low word of the median, graph ~2048) is nonzero.
    const int* b32 = (const int*)batch;
    const bool is64 = (b32[n - 1] == 0) && (b32[n - 2] != 0);

    const int s = lbound(batch, is64, n, g);
    const int e = lbound(batch, is64, n, g + 1);

    // W fragment: lane l owns columns 4l..4l+3
    const float4 wv  = ((const float4*)W)[lane];
    const float bias = b[0];

    float4 asum = make_float4(0.f, 0.f, 0.f, 0.f);
    float4 amax = make_float4(-INFINITY, -INFINITY, -INFINITY, -INFINITY);

    const float4* xv4 = (const float4*)x;
    for (int r = s + w; r < e; r += 4) {
        const float4 xv = xv4[(size_t)r * 64 + lane];
        // partial dot with W
        float p = xv.x * wv.x + xv.y * wv.y + xv.z * wv.z + xv.w * wv.w;
        // 64-lane butterfly reduce: every lane ends with the full dot
        p += __shfl_xor(p, 32, 64);
        p += __shfl_xor(p, 16, 64);
        p += __shfl_xor(p,  8, 64);
        p += __shfl_xor(p,  4, 64);
        p += __shfl_xor(p,  2, 64);
        p += __shfl_xor(p,  1, 64);
        const float sc = 1.0f / (1.0f + __expf(-(p + bias)));
        asum.x = fmaf(sc, xv.x, asum.x);
        asum.y = fmaf(sc, xv.y, asum.y);
        asum.z = fmaf(sc, xv.z, asum.z);
        asum.w = fmaf(sc, xv.w, asum.w);
        amax.x = fmaxf(amax.x, xv.x);
        amax.y = fmaxf(amax.y, xv.y);
        amax.z = fmaxf(amax.z, xv.z);
        amax.w = fmaxf(amax.w, xv.w);
    }

    // cross-wave combine via LDS
    __shared__ float lsum[4][DIM];
    __shared__ float lmax[4][DIM];
    *(float4*)&lsum[w][lane * 4] = asum;
    *(float4*)&lmax[w][lane * 4] = amax;
    __syncthreads();

    const int c = tid;  // 0..255 = column
    const float s4 = (lsum[0][c] + lsum[1][c]) + (lsum[2][c] + lsum[3][c]);
    const float m4 = fmaxf(fmaxf(lmax[0][c], lmax[1][c]), fmaxf(lmax[2][c], lmax[3][c]));

    const size_t ob = (size_t)g * (2 * DIM);
    out[ob + c]       = s4;   // segment_sum(gated)
    out[ob + DIM + c] = m4;   // segment_max(x)
}

extern "C" void kernel_launch(void* const* d_in, const int* in_sizes, int n_in,
                              void* d_out, int out_size, void* d_ws, size_t ws_size,
                              hipStream_t stream) {
    const float* x     = (const float*)d_in[0];
    const void*  batch = (const void*)d_in[1];
    const float* W     = (const float*)d_in[2];
    const float* b     = (const float*)d_in[3];
    float* out = (float*)d_out;

    const int n       = in_sizes[0] / DIM;       // number of nodes
    const int ngraphs = out_size / (2 * DIM);    // 4096

    readout_kernel<<<dim3(ngraphs), dim3(256), 0, stream>>>(x, batch, W, b, out, n);
}